// Round 1
// baseline (252.922 us; speedup 1.0000x reference)
//
#include <hip/hip_runtime.h>

// Problem constants: B=64, T=128, N=128, M=512, 4M=2048, BT=8192
#define FMA4(A,S,V) {(A).x+=(S)*(V).x; (A).y+=(S)*(V).y; (A).z+=(S)*(V).z; (A).w+=(S)*(V).w;}

__device__ __forceinline__ float fast_rcp(float x){
#if __has_builtin(__builtin_amdgcn_rcpf)
  return __builtin_amdgcn_rcpf(x);
#else
  return 1.0f/x;
#endif
}
__device__ __forceinline__ float sigm(float x){ return fast_rcp(1.0f + __expf(-x)); }
__device__ __forceinline__ float tanh_f(float x){ return 1.0f - 2.0f*fast_rcp(__expf(2.0f*x) + 1.0f); }
__device__ __forceinline__ float bf2f(unsigned short u){ return __uint_as_float(((unsigned)u)<<16); }
__device__ __forceinline__ unsigned short f2bf(float f){
  unsigned u = __float_as_uint(f);
  return (unsigned short)((u + 0x7fffu + ((u>>16)&1u)) >> 16);
}

// K1: Uh[b][j] = sum_k h0[b][k]*U_lstm[k][j] + b_lstm[j]   (64 x 2048, K=512)
// grid (8 j-chunks, 8 b-chunks of 8), block 256
__global__ __launch_bounds__(256) void k1_uh(const float* __restrict__ h0,
                                             const float* __restrict__ Ul,
                                             const float* __restrict__ bl,
                                             float* __restrict__ Uh){
  __shared__ float h0s[8*512];
  const int tid = threadIdx.x;
  const int jc = blockIdx.x, bc = blockIdx.y;
  const int j = jc*256 + tid;
  for (int idx = tid; idx < 8*512; idx += 256) h0s[idx] = h0[bc*8*512 + idx];
  __syncthreads();
  float acc[8];
#pragma unroll
  for (int i=0;i<8;i++) acc[i]=0.f;
  for (int k=0;k<512;k+=4){
    float w0 = Ul[(k+0)*2048 + j];
    float w1 = Ul[(k+1)*2048 + j];
    float w2 = Ul[(k+2)*2048 + j];
    float w3 = Ul[(k+3)*2048 + j];
#pragma unroll
    for (int i=0;i<8;i++){
      float4 hv = *(const float4*)&h0s[i*512 + k];
      acc[i] += hv.x*w0 + hv.y*w1 + hv.z*w2 + hv.w*w3;
    }
  }
  const float bj = bl[j];
#pragma unroll
  for (int i=0;i<8;i++) Uh[(bc*8+i)*2048 + j] = acc[i] + bj;
}

// K2: z = X@W_lstm + Uh -> gates -> hc (bf16, [h|c])   tile 64 rows x (4 gates x 64 m)
// grid (8 m-chunks, 128 row-chunks), block 256
__global__ __launch_bounds__(256) void k2_gates(const float* __restrict__ X,
                                                const float* __restrict__ Wl,
                                                const float* __restrict__ Uh,
                                                const float* __restrict__ s0,
                                                unsigned short* __restrict__ hc){
  __shared__ float Xs[32][68];    // [k][row]
  __shared__ float Ws[32][260];   // [k][4*64 cols]
  const int tid = threadIdx.x;
  const int mc = blockIdx.x;      // 0..7
  const int rc = blockIdx.y;      // 0..127
  const int bt0 = rc*64;
  const int b = bt0 >> 7;
  const int tr = tid >> 4, tc = tid & 15;
  float4 acc[4][4];               // [gate][row]: float4 over 4 cols
#pragma unroll
  for (int g=0; g<4; g++)
#pragma unroll
    for (int r=0; r<4; r++){ acc[g][r].x=0.f; acc[g][r].y=0.f; acc[g][r].z=0.f; acc[g][r].w=0.f; }

  for (int kc=0; kc<4; kc++){
#pragma unroll
    for (int i=0;i<2;i++){
      int idx = tid + i*256;              // 512 float4: 64 rows x 8 quads
      int row = idx>>3, kq = idx&7;
      float4 xv = *(const float4*)&X[(bt0+row)*128 + kc*32 + kq*4];
      Xs[kq*4+0][row]=xv.x; Xs[kq*4+1][row]=xv.y; Xs[kq*4+2][row]=xv.z; Xs[kq*4+3][row]=xv.w;
    }
#pragma unroll
    for (int i=0;i<8;i++){
      int idx = tid + i*256;              // 2048 float4: 32 k x (4g x 16 quads)
      int k = idx>>6, q = idx&63, g = q>>4, c4 = q&15;
      *(float4*)&Ws[k][g*64 + c4*4] = *(const float4*)&Wl[(kc*32+k)*2048 + g*512 + mc*64 + c4*4];
    }
    __syncthreads();
#pragma unroll 4
    for (int kk=0; kk<32; kk++){
      float4 xv = *(const float4*)&Xs[kk][tr*4];
      float4 w0 = *(const float4*)&Ws[kk][0*64 + tc*4];
      float4 w1 = *(const float4*)&Ws[kk][1*64 + tc*4];
      float4 w2 = *(const float4*)&Ws[kk][2*64 + tc*4];
      float4 w3 = *(const float4*)&Ws[kk][3*64 + tc*4];
      FMA4(acc[0][0], xv.x, w0); FMA4(acc[0][1], xv.y, w0); FMA4(acc[0][2], xv.z, w0); FMA4(acc[0][3], xv.w, w0);
      FMA4(acc[1][0], xv.x, w1); FMA4(acc[1][1], xv.y, w1); FMA4(acc[1][2], xv.z, w1); FMA4(acc[1][3], xv.w, w1);
      FMA4(acc[2][0], xv.x, w2); FMA4(acc[2][1], xv.y, w2); FMA4(acc[2][2], xv.z, w2); FMA4(acc[2][3], xv.w, w2);
      FMA4(acc[3][0], xv.x, w3); FMA4(acc[3][1], xv.y, w3); FMA4(acc[3][2], xv.z, w3); FMA4(acc[3][3], xv.w, w3);
    }
    __syncthreads();
  }

  // epilogue: add Uh, gates, write hc as bf16
  const float4 uh0 = *(const float4*)&Uh[b*2048 + 0*512 + mc*64 + tc*4];
  const float4 uh1 = *(const float4*)&Uh[b*2048 + 1*512 + mc*64 + tc*4];
  const float4 uh2 = *(const float4*)&Uh[b*2048 + 2*512 + mc*64 + tc*4];
  const float4 uh3 = *(const float4*)&Uh[b*2048 + 3*512 + mc*64 + tc*4];
  const float4 s04 = *(const float4*)&s0[b*512 + mc*64 + tc*4];
#pragma unroll
  for (int rr=0; rr<4; rr++){
    const int bt = bt0 + tr*4 + rr;
    ushort4 hq, cq;
#define GATECC(AX) { \
    float zi = acc[0][rr].AX + uh0.AX; \
    float zf = acc[1][rr].AX + uh1.AX; \
    float zc = acc[2][rr].AX + uh2.AX; \
    float zo = acc[3][rr].AX + uh3.AX; \
    float fi = sigm(zi), ff = sigm(zf), fo = sigm(zo); \
    float cv = ff*s04.AX + fi*tanh_f(zc); \
    float hv = fo*tanh_f(cv); \
    hq.AX = f2bf(hv); cq.AX = f2bf(cv); }
    GATECC(x) GATECC(y) GATECC(z) GATECC(w)
#undef GATECC
    *(ushort4*)&hc[bt*1024 + mc*64 + tc*4]       = hq;
    *(ushort4*)&hc[bt*1024 + 512 + mc*64 + tc*4] = cq;
  }
}

// K3: A = hc @ W_e + b_We   (8192 x 128, K=1024), hc is bf16
// grid (2 col-halves, 128 row-chunks), block 256, tile 64x64
__global__ __launch_bounds__(256) void k3_A(const unsigned short* __restrict__ hc,
                                            const float* __restrict__ We,
                                            const float* __restrict__ bWe,
                                            float* __restrict__ A){
  __shared__ float hs[64][68];   // [k][row]
  __shared__ float es[64][68];   // [k][col]
  const int tid = threadIdx.x;
  const int nb = blockIdx.x;     // 0..1
  const int rc = blockIdx.y;     // 0..127
  const int bt0 = rc*64;
  const int tr = tid>>4, tc = tid&15;
  float4 acc[4];
#pragma unroll
  for (int r=0;r<4;r++){ acc[r].x=0.f; acc[r].y=0.f; acc[r].z=0.f; acc[r].w=0.f; }

  for (int kc=0; kc<16; kc++){
#pragma unroll
    for (int i=0;i<4;i++){
      int idx = tid + i*256;             // 1024: 64 rows x 16 k-quads
      int row = idx>>4, kq = idx&15;
      ushort4 u4 = *(const ushort4*)&hc[(bt0+row)*1024 + kc*64 + kq*4];
      hs[kq*4+0][row] = bf2f(u4.x); hs[kq*4+1][row] = bf2f(u4.y);
      hs[kq*4+2][row] = bf2f(u4.z); hs[kq*4+3][row] = bf2f(u4.w);
    }
#pragma unroll
    for (int i=0;i<4;i++){
      int idx = tid + i*256;             // 1024 float4: 64 k x 16 quads
      int k = idx>>4, cq = idx&15;
      *(float4*)&es[k][cq*4] = *(const float4*)&We[(kc*64+k)*128 + nb*64 + cq*4];
    }
    __syncthreads();
#pragma unroll 4
    for (int k=0;k<64;k++){
      float4 xv = *(const float4*)&hs[k][tr*4];
      float4 wv = *(const float4*)&es[k][tc*4];
      FMA4(acc[0], xv.x, wv); FMA4(acc[1], xv.y, wv); FMA4(acc[2], xv.z, wv); FMA4(acc[3], xv.w, wv);
    }
    __syncthreads();
  }
  const float4 bv = *(const float4*)&bWe[nb*64 + tc*4];
#pragma unroll
  for (int rr=0; rr<4; rr++){
    float4 o = acc[rr]; o.x+=bv.x; o.y+=bv.y; o.z+=bv.z; o.w+=bv.w;
    *(float4*)&A[(bt0 + tr*4 + rr)*128 + nb*64 + tc*4] = o;
  }
}

// K4: UT[b][k][n] = sum_t X[b][t][n]*U_e[t][k] + b_Ue[k]   (k-major for K5)
// grid (2 n-halves, 64 b), block 256
__global__ __launch_bounds__(256) void k4_U(const float* __restrict__ X,
                                            const float* __restrict__ Ue,
                                            const float* __restrict__ bUe,
                                            float* __restrict__ UT){
  __shared__ float Xs[32][68];    // [t][n]
  __shared__ float Us[32][132];   // [t][k]
  const int tid = threadIdx.x;
  const int nh = blockIdx.x;      // 0..1
  const int b  = blockIdx.y;      // 0..63
  const int tr = tid>>4, tc = tid&15;
  float4 acc[8];                  // k-major, float4 over n
#pragma unroll
  for (int i=0;i<8;i++){ acc[i].x=0.f; acc[i].y=0.f; acc[i].z=0.f; acc[i].w=0.f; }

  for (int tk=0; tk<4; tk++){
#pragma unroll
    for (int i=0;i<2;i++){
      int idx = tid + i*256;            // 512 float4: 32 t x 16 n-quads
      int t = idx>>4, nq = idx&15;
      *(float4*)&Xs[t][nq*4] = *(const float4*)&X[(b*128 + tk*32 + t)*128 + nh*64 + nq*4];
    }
#pragma unroll
    for (int i=0;i<4;i++){
      int idx = tid + i*256;            // 1024 float4: 32 t x 32 k-quads
      int t = idx>>5, kq = idx&31;
      *(float4*)&Us[t][kq*4] = *(const float4*)&Ue[(tk*32+t)*128 + kq*4];
    }
    __syncthreads();
#pragma unroll 4
    for (int t=0;t<32;t++){
      float4 xv = *(const float4*)&Xs[t][tr*4];
      float4 u0 = *(const float4*)&Us[t][tc*4];
      float4 u1 = *(const float4*)&Us[t][64 + tc*4];
      FMA4(acc[0], u0.x, xv); FMA4(acc[1], u0.y, xv); FMA4(acc[2], u0.z, xv); FMA4(acc[3], u0.w, xv);
      FMA4(acc[4], u1.x, xv); FMA4(acc[5], u1.y, xv); FMA4(acc[6], u1.z, xv); FMA4(acc[7], u1.w, xv);
    }
    __syncthreads();
  }
#pragma unroll
  for (int kk=0; kk<8; kk++){
    int k = (kk<4) ? (tc*4+kk) : (64 + tc*4 + (kk-4));
    float bu = bUe[k];
    float4 o = acc[kk]; o.x+=bu; o.y+=bu; o.z+=bu; o.w+=bu;
    *(float4*)&UT[(b*128 + k)*128 + nh*64 + tr*4] = o;
  }
}

// K5: scores[t,n] = sum_k tanh(A[t,k]+U[n,k])*v[k]; softmax over n; out = X*alpha
// grid (8 t-chunks of 16, 64 b), block 256 (2 t's in flight: threads (tpair, n))
__global__ __launch_bounds__(256) void k5_score(const float* __restrict__ X,
                                                const float* __restrict__ UT,
                                                const float* __restrict__ A,
                                                const float* __restrict__ ve,
                                                float* __restrict__ out){
  __shared__ float Us[128][132];  // [k][n]
  __shared__ float As[16][128];   // [t_local][k]
  __shared__ float vs[128];
  __shared__ float redm[4], reds[4];
  const int tid = threadIdx.x;
  const int tch = blockIdx.x;     // 0..7
  const int b   = blockIdx.y;     // 0..63
  const int tpair = tid>>7, n = tid&127;
  const int wid = tid>>6;

#pragma unroll
  for (int i=0;i<16;i++){
    int idx = tid + i*256;             // 4096 float4: 128 k x 32 n-quads
    int k = idx>>5, nq = idx&31;
    *(float4*)&Us[k][nq*4] = *(const float4*)&UT[(b*128+k)*128 + nq*4];
  }
#pragma unroll
  for (int i=0;i<2;i++){
    int idx = tid + i*256;             // 512 float4: 16 t x 32 k-quads
    int tl = idx>>5, kq = idx&31;
    *(float4*)&As[tl][kq*4] = *(const float4*)&A[(b*128 + tch*16 + tl)*128 + kq*4];
  }
  if (tid < 32) *(float4*)&vs[tid*4] = *(const float4*)&ve[tid*4];
  __syncthreads();

  for (int tt=0; tt<8; tt++){
    const int tl = tt*2 + tpair;
    float score = 0.f;
    const float* Arow = As[tl];
#pragma unroll 2
    for (int k4=0; k4<32; k4++){
      float4 a4 = *(const float4*)&Arow[k4*4];
      float4 v4 = *(const float4*)&vs[k4*4];
      int k = k4*4;
      score += tanh_f(a4.x + Us[k+0][n]) * v4.x;
      score += tanh_f(a4.y + Us[k+1][n]) * v4.y;
      score += tanh_f(a4.z + Us[k+2][n]) * v4.z;
      score += tanh_f(a4.w + Us[k+3][n]) * v4.w;
    }
    // softmax over n=128 (2 waves per t)
    float m = score;
#pragma unroll
    for (int off=32; off>0; off>>=1) m = fmaxf(m, __shfl_xor(m, off));
    if ((tid&63)==0) redm[wid] = m;
    __syncthreads();
    const float M = fmaxf(redm[tpair*2], redm[tpair*2+1]);
    const float e = __expf(score - M);
    float s = e;
#pragma unroll
    for (int off=32; off>0; off>>=1) s += __shfl_xor(s, off);
    if ((tid&63)==0) reds[wid] = s;
    __syncthreads();
    const float S = reds[tpair*2] + reds[tpair*2+1];
    const float alpha = e * fast_rcp(S);
    const int t = tch*16 + tl;
    const int g = (b*128 + t)*128 + n;
    out[g] = X[g] * alpha;
  }
}

extern "C" void kernel_launch(void* const* d_in, const int* in_sizes, int n_in,
                              void* d_out, int out_size, void* d_ws, size_t ws_size,
                              hipStream_t stream){
  (void)in_sizes; (void)n_in; (void)out_size; (void)ws_size;
  const float* X   = (const float*)d_in[0];
  const float* h0  = (const float*)d_in[1];
  const float* s0  = (const float*)d_in[2];
  const float* Wl  = (const float*)d_in[3];
  const float* Ul  = (const float*)d_in[4];
  const float* bl  = (const float*)d_in[5];
  const float* We  = (const float*)d_in[6];
  const float* bWe = (const float*)d_in[7];
  const float* Ue  = (const float*)d_in[8];
  const float* bUe = (const float*)d_in[9];
  const float* ve  = (const float*)d_in[10];
  // d_in[11] (b_ve) is softmax-shift-invariant: skipped.
  float* out = (float*)d_out;

  char* ws = (char*)d_ws;
  float*          Uh = (float*)ws;                                   // 64x2048 f32   (512 KB)
  unsigned short* hc = (unsigned short*)(ws + 524288);               // 8192x1024 bf16 (16 MB)
  float*          A  = (float*)(ws + 524288 + 16777216);             // 8192x128 f32  (4 MB)
  float*          UT = (float*)(ws + 524288 + 16777216 + 4194304);   // 64x128x128 f32 (4 MB)

  k1_uh   <<<dim3(8,8),   256, 0, stream>>>(h0, Ul, bl, Uh);
  k2_gates<<<dim3(8,128), 256, 0, stream>>>(X, Wl, Uh, s0, hc);
  k4_U    <<<dim3(2,64),  256, 0, stream>>>(X, Ue, bUe, UT);
  k3_A    <<<dim3(2,128), 256, 0, stream>>>(hc, We, bWe, A);
  k5_score<<<dim3(8,64),  256, 0, stream>>>(X, UT, A, ve, out);
}

// Round 2
// 132.928 us; speedup vs baseline: 1.9027x; 1.9027x over previous
//
#include <hip/hip_runtime.h>

// B=64, T=128, N=128, M=512, 4M=2048, BT=8192
typedef __attribute__((ext_vector_type(8))) short bfrag;   // 8 bf16 = 4 VGPR
typedef __attribute__((ext_vector_type(4))) float f32x4;

#define FMA4(A,S,V) {(A).x+=(S)*(V).x; (A).y+=(S)*(V).y; (A).z+=(S)*(V).z; (A).w+=(S)*(V).w;}

__device__ __forceinline__ float fast_rcp(float x){
#if __has_builtin(__builtin_amdgcn_rcpf)
  return __builtin_amdgcn_rcpf(x);
#else
  return 1.0f/x;
#endif
}
__device__ __forceinline__ float sigm(float x){ return fast_rcp(1.0f + __expf(-x)); }
__device__ __forceinline__ float tanh_f(float x){ return 1.0f - 2.0f*fast_rcp(__expf(2.0f*x) + 1.0f); }
__device__ __forceinline__ float bf2f(unsigned short u){ return __uint_as_float(((unsigned)u)<<16); }
__device__ __forceinline__ unsigned short f2bf(float f){
  unsigned u = __float_as_uint(f);
  return (unsigned short)((u + 0x7fffu + ((u>>16)&1u)) >> 16);
}

// ---------------------------------------------------------------------------
// P: transpose f32 [K][N] -> bf16 [N][K].  grid (N/64, K/64), block 256
__global__ __launch_bounds__(256) void transp_bf(const float* __restrict__ in,
                                                 unsigned short* __restrict__ out,
                                                 int K, int N){
  __shared__ float t[64][68];
  const int tid = threadIdx.x;
  const int j0 = blockIdx.x*64, k0 = blockIdx.y*64;
#pragma unroll
  for (int i=0;i<4;i++){
    int idx = tid + i*256;           // 1024 float4: 64 k-rows x 16 quads
    int r = idx>>4, c4 = idx&15;
    *(float4*)&t[r][c4*4] = *(const float4*)&in[(k0+r)*N + j0 + c4*4];
  }
  __syncthreads();
#pragma unroll
  for (int i=0;i<4;i++){
    int idx = tid + i*256;           // 1024 ushort4: 64 n-rows x 16 quads
    int r = idx>>4, c4 = idx&15;
    ushort4 o;
    o.x = f2bf(t[c4*4+0][r]); o.y = f2bf(t[c4*4+1][r]);
    o.z = f2bf(t[c4*4+2][r]); o.w = f2bf(t[c4*4+3][r]);
    *(ushort4*)&out[(j0+r)*K + k0 + c4*4] = o;
  }
}

// ---------------------------------------------------------------------------
// K1: Uhp[kc][b][j] = sum_{k in kc-chunk} h0[b][k]*Ul[k][j]   (partials; bias in K2)
// grid (16 jc, 16 = 4 bc x 4 kc), block 256 (128 j x 2 b-halves)
__global__ __launch_bounds__(256) void k1_part(const float* __restrict__ h0,
                                               const float* __restrict__ Ul,
                                               float* __restrict__ Uhp){
  __shared__ float h0s[16][128];
  const int tid = threadIdx.x;
  const int jc = blockIdx.x;
  const int bc = blockIdx.y >> 2, kc = blockIdx.y & 3;
#pragma unroll
  for (int i=0;i<2;i++){
    int idx = tid + i*256;           // 512 float4: 16 b x 32 k-quads
    int bi = idx>>5, kq = idx&31;
    *(float4*)&h0s[bi][kq*4] = *(const float4*)&h0[(bc*16+bi)*512 + kc*128 + kq*4];
  }
  __syncthreads();
  const int jj = tid & 127, bh = tid >> 7;
  const int j = jc*128 + jj;
  float acc[8];
#pragma unroll
  for (int i=0;i<8;i++) acc[i]=0.f;
  for (int k=0;k<128;k+=4){
    float w0 = Ul[(kc*128+k+0)*2048 + j];
    float w1 = Ul[(kc*128+k+1)*2048 + j];
    float w2 = Ul[(kc*128+k+2)*2048 + j];
    float w3 = Ul[(kc*128+k+3)*2048 + j];
#pragma unroll
    for (int bi=0;bi<8;bi++){
      float4 h4 = *(const float4*)&h0s[bh*8+bi][k];
      acc[bi] += h4.x*w0 + h4.y*w1 + h4.z*w2 + h4.w*w3;
    }
  }
#pragma unroll
  for (int bi=0;bi<8;bi++)
    Uhp[kc*131072 + (bc*16 + bh*8 + bi)*2048 + j] = acc[bi];
}

// ---------------------------------------------------------------------------
// K2: z = X@Wl + Uh -> gates -> hc bf16.  MFMA 16x16x32 bf16.
// Block tile: 128 rows (one b) x 128 cols; cols interleave 4 gates at 16-col
// granularity: col c -> q=c>>4, gate=q&3, m = mc*32 + (q>>2)*16 + (c&15).
// grid (16 mc, 64 b), block 256 (4 waves, 2x2 of 64x64)
__global__ __launch_bounds__(256) void k2_mfma(const float* __restrict__ X,
                                               const unsigned short* __restrict__ Wlt,
                                               const float* __restrict__ Uhp,
                                               const float* __restrict__ bl,
                                               const float* __restrict__ s0,
                                               unsigned short* __restrict__ hc){
  __shared__ __align__(16) char lds[65536];   // Xs [128][256B swz] | Ws [128][256B swz]
  const int tid = threadIdx.x;
  const int mc = blockIdx.x;       // 0..15
  const int b  = blockIdx.y;       // 0..63
  const int bt0 = b*128;
  const int lane = tid & 63, wave = tid >> 6;
  const int wr = wave >> 1, wc = wave & 1;

  // stage X (f32 -> bf16, swizzled rows of 256B)
#pragma unroll
  for (int i=0;i<16;i++){
    int idx = tid + i*256;           // 4096 float4: 128 rows x 32 quads
    int r = idx>>5, q = idx&31;
    float4 xv = *(const float4*)&X[(bt0+r)*128 + q*4];
    ushort4 u; u.x=f2bf(xv.x); u.y=f2bf(xv.y); u.z=f2bf(xv.z); u.w=f2bf(xv.w);
    int byte = r*256 + ((q*8) ^ ((r&7)<<4));
    *(ushort4*)&lds[byte] = u;
  }
  // stage W (bf16 col-major source, gate-interleaved rows, swizzled)
#pragma unroll
  for (int i=0;i<8;i++){
    int idx = tid + i*256;           // 2048 granules: 128 c-rows x 16
    int c = idx>>4, gr = idx&15;
    int q = c>>4, cm = c&15;
    int j = (q&3)*512 + mc*32 + ((q>>2)<<4) + cm;
    uint4 wv = *(const uint4*)&Wlt[j*128 + gr*8];
    int byte = 32768 + c*256 + ((gr*16) ^ ((c&7)<<4));
    *(uint4*)&lds[byte] = wv;
  }
  __syncthreads();

  f32x4 acc[4][4];
#pragma unroll
  for (int mt=0;mt<4;mt++)
#pragma unroll
    for (int nt=0;nt<4;nt++) acc[mt][nt] = (f32x4){0.f,0.f,0.f,0.f};

#pragma unroll
  for (int ks=0;ks<4;ks++){
    const int kb = ks*64 + ((lane>>4)<<4);   // byte offset of k within row
    bfrag a[4], bb[4];
#pragma unroll
    for (int mt=0;mt<4;mt++){
      int r = wr*64 + mt*16 + (lane&15);
      a[mt] = *(const bfrag*)&lds[r*256 + (kb ^ ((r&7)<<4))];
    }
#pragma unroll
    for (int nt=0;nt<4;nt++){
      int c = wc*64 + nt*16 + (lane&15);
      bb[nt] = *(const bfrag*)&lds[32768 + c*256 + (kb ^ ((c&7)<<4))];
    }
#pragma unroll
    for (int mt=0;mt<4;mt++)
#pragma unroll
      for (int nt=0;nt<4;nt++)
        acc[mt][nt] = __builtin_amdgcn_mfma_f32_16x16x32_bf16(a[mt], bb[nt], acc[mt][nt], 0, 0, 0);
  }

  // epilogue: Uh partials + bias, gates, bf16 store
  const int mloc = mc*32 + wc*16 + (lane&15);     // 0..511
  float uh[4];
#pragma unroll
  for (int g=0;g<4;g++){
    int j = g*512 + mloc;
    uh[g] = bl[j] + Uhp[0*131072 + b*2048 + j] + Uhp[1*131072 + b*2048 + j]
                  + Uhp[2*131072 + b*2048 + j] + Uhp[3*131072 + b*2048 + j];
  }
  const float s0v = s0[b*512 + mloc];
#pragma unroll
  for (int mt=0;mt<4;mt++){
#pragma unroll
    for (int reg=0;reg<4;reg++){
      int row = wr*64 + mt*16 + (lane>>4)*4 + reg;
      float zi = acc[mt][0][reg] + uh[0];
      float zf = acc[mt][1][reg] + uh[1];
      float zc = acc[mt][2][reg] + uh[2];
      float zo = acc[mt][3][reg] + uh[3];
      float fi = sigm(zi), ff = sigm(zf), fo = sigm(zo);
      float cv = ff*s0v + fi*tanh_f(zc);
      float hv = fo*tanh_f(cv);
      hc[(bt0+row)*1024 + mloc]       = f2bf(hv);
      hc[(bt0+row)*1024 + 512 + mloc] = f2bf(cv);
    }
  }
}

// ---------------------------------------------------------------------------
// K3: Ap[kc] = hc(bf16) @ Wet^T partial over K-chunk of 256.  MFMA.
// grid (4 kc, 64 row-chunks), block 256 (4 waves 2x2 of 64x64), BN=128=all n
__global__ __launch_bounds__(256) void k3_mfma(const unsigned short* __restrict__ hc,
                                               const unsigned short* __restrict__ Wet,
                                               float* __restrict__ Ap){
  __shared__ __align__(16) char lds[32768];  // hcs 16KB | wes 16KB (rows of 128B swz)
  const int tid = threadIdx.x;
  const int kc = blockIdx.x;       // 0..3
  const int rc = blockIdx.y;       // 0..63
  const int bt0 = rc*128;
  const int lane = tid & 63, wave = tid >> 6;
  const int wr = wave >> 1, wc = wave & 1;

  f32x4 acc[4][4];
#pragma unroll
  for (int mt=0;mt<4;mt++)
#pragma unroll
    for (int nt=0;nt<4;nt++) acc[mt][nt] = (f32x4){0.f,0.f,0.f,0.f};

  for (int it=0; it<4; it++){
    const int k0 = kc*256 + it*64;
#pragma unroll
    for (int i=0;i<4;i++){
      int idx = tid + i*256;         // 1024 granules: 128 rows x 8
      int r = idx>>3, gr = idx&7;
      uint4 v = *(const uint4*)&hc[(bt0+r)*1024 + k0 + gr*8];
      int byte = r*128 + ((gr*16) ^ ((r&7)<<4));
      *(uint4*)&lds[byte] = v;
    }
#pragma unroll
    for (int i=0;i<4;i++){
      int idx = tid + i*256;
      int n = idx>>3, gr = idx&7;
      uint4 v = *(const uint4*)&Wet[n*1024 + k0 + gr*8];
      int byte = 16384 + n*128 + ((gr*16) ^ ((n&7)<<4));
      *(uint4*)&lds[byte] = v;
    }
    __syncthreads();
#pragma unroll
    for (int kk=0;kk<2;kk++){
      const int kb = kk*64 + ((lane>>4)<<4);
      bfrag a[4], bb[4];
#pragma unroll
      for (int mt=0;mt<4;mt++){
        int r = wr*64 + mt*16 + (lane&15);
        a[mt] = *(const bfrag*)&lds[r*128 + (kb ^ ((r&7)<<4))];
      }
#pragma unroll
      for (int nt=0;nt<4;nt++){
        int n = wc*64 + nt*16 + (lane&15);
        bb[nt] = *(const bfrag*)&lds[16384 + n*128 + (kb ^ ((n&7)<<4))];
      }
#pragma unroll
      for (int mt=0;mt<4;mt++)
#pragma unroll
        for (int nt=0;nt<4;nt++)
          acc[mt][nt] = __builtin_amdgcn_mfma_f32_16x16x32_bf16(a[mt], bb[nt], acc[mt][nt], 0, 0, 0);
    }
    __syncthreads();
  }
#pragma unroll
  for (int mt=0;mt<4;mt++)
#pragma unroll
    for (int reg=0;reg<4;reg++){
      int row = wr*64 + mt*16 + (lane>>4)*4 + reg;
#pragma unroll
      for (int nt=0;nt<4;nt++){
        int col = wc*64 + nt*16 + (lane&15);
        Ap[kc*1048576 + (bt0+row)*128 + col] = acc[mt][nt][reg];
      }
    }
}

// ---------------------------------------------------------------------------
// K4: UT[b][k][n] = sum_t X[b][t][n]*U_e[t][k] + b_Ue[k]   (k-major for K5)
// grid (2 n-halves, 64 b), block 256
__global__ __launch_bounds__(256) void k4_U(const float* __restrict__ X,
                                            const float* __restrict__ Ue,
                                            const float* __restrict__ bUe,
                                            float* __restrict__ UT){
  __shared__ float Xs[32][68];    // [t][n]
  __shared__ float Us[32][132];   // [t][k]
  const int tid = threadIdx.x;
  const int nh = blockIdx.x;      // 0..1
  const int b  = blockIdx.y;      // 0..63
  const int tr = tid>>4, tc = tid&15;
  float4 acc[8];
#pragma unroll
  for (int i=0;i<8;i++){ acc[i].x=0.f; acc[i].y=0.f; acc[i].z=0.f; acc[i].w=0.f; }

  for (int tk=0; tk<4; tk++){
#pragma unroll
    for (int i=0;i<2;i++){
      int idx = tid + i*256;
      int t = idx>>4, nq = idx&15;
      *(float4*)&Xs[t][nq*4] = *(const float4*)&X[(b*128 + tk*32 + t)*128 + nh*64 + nq*4];
    }
#pragma unroll
    for (int i=0;i<4;i++){
      int idx = tid + i*256;
      int t = idx>>5, kq = idx&31;
      *(float4*)&Us[t][kq*4] = *(const float4*)&Ue[(tk*32+t)*128 + kq*4];
    }
    __syncthreads();
#pragma unroll 4
    for (int t=0;t<32;t++){
      float4 xv = *(const float4*)&Xs[t][tr*4];
      float4 u0 = *(const float4*)&Us[t][tc*4];
      float4 u1 = *(const float4*)&Us[t][64 + tc*4];
      FMA4(acc[0], u0.x, xv); FMA4(acc[1], u0.y, xv); FMA4(acc[2], u0.z, xv); FMA4(acc[3], u0.w, xv);
      FMA4(acc[4], u1.x, xv); FMA4(acc[5], u1.y, xv); FMA4(acc[6], u1.z, xv); FMA4(acc[7], u1.w, xv);
    }
    __syncthreads();
  }
#pragma unroll
  for (int kk=0; kk<8; kk++){
    int k = (kk<4) ? (tc*4+kk) : (64 + tc*4 + (kk-4));
    float bu = bUe[k];
    float4 o = acc[kk]; o.x+=bu; o.y+=bu; o.z+=bu; o.w+=bu;
    *(float4*)&UT[(b*128 + k)*128 + nh*64 + tr*4] = o;
  }
}

// ---------------------------------------------------------------------------
// K5: scores[t,n] = sum_k tanh(A[t,k]+U[n,k])*v[k]; softmax over n; out = X*alpha
// A assembled from 4 split-K partials + b_We.  grid (8 t-chunks, 64 b), block 256
__global__ __launch_bounds__(256) void k5_score(const float* __restrict__ X,
                                                const float* __restrict__ UT,
                                                const float* __restrict__ Ap,
                                                const float* __restrict__ bWe,
                                                const float* __restrict__ ve,
                                                float* __restrict__ out){
  __shared__ float Us[128][132];  // [k][n]
  __shared__ float As[16][128];   // [t_local][k]
  __shared__ float vs[128];
  __shared__ float redm[4], reds[4];
  const int tid = threadIdx.x;
  const int tch = blockIdx.x;     // 0..7
  const int b   = blockIdx.y;     // 0..63
  const int tpair = tid>>7, n = tid&127;
  const int wid = tid>>6;

#pragma unroll
  for (int i=0;i<16;i++){
    int idx = tid + i*256;
    int k = idx>>5, nq = idx&31;
    *(float4*)&Us[k][nq*4] = *(const float4*)&UT[(b*128+k)*128 + nq*4];
  }
#pragma unroll
  for (int i=0;i<2;i++){
    int idx = tid + i*256;
    int tl = idx>>5, kq = idx&31;
    int ra = (b*128 + tch*16 + tl)*128 + kq*4;
    float4 a0 = *(const float4*)&Ap[0*1048576 + ra];
    float4 a1 = *(const float4*)&Ap[1*1048576 + ra];
    float4 a2 = *(const float4*)&Ap[2*1048576 + ra];
    float4 a3 = *(const float4*)&Ap[3*1048576 + ra];
    float4 bv = *(const float4*)&bWe[kq*4];
    float4 s; s.x = a0.x+a1.x+a2.x+a3.x+bv.x; s.y = a0.y+a1.y+a2.y+a3.y+bv.y;
    s.z = a0.z+a1.z+a2.z+a3.z+bv.z; s.w = a0.w+a1.w+a2.w+a3.w+bv.w;
    *(float4*)&As[tl][kq*4] = s;
  }
  if (tid < 32) *(float4*)&vs[tid*4] = *(const float4*)&ve[tid*4];
  __syncthreads();

  for (int tt=0; tt<8; tt++){
    const int tl = tt*2 + tpair;
    float score = 0.f;
    const float* Arow = As[tl];
#pragma unroll 2
    for (int k4=0; k4<32; k4++){
      float4 a4 = *(const float4*)&Arow[k4*4];
      float4 v4 = *(const float4*)&vs[k4*4];
      int k = k4*4;
      score += tanh_f(a4.x + Us[k+0][n]) * v4.x;
      score += tanh_f(a4.y + Us[k+1][n]) * v4.y;
      score += tanh_f(a4.z + Us[k+2][n]) * v4.z;
      score += tanh_f(a4.w + Us[k+3][n]) * v4.w;
    }
    float m = score;
#pragma unroll
    for (int off=32; off>0; off>>=1) m = fmaxf(m, __shfl_xor(m, off));
    if ((tid&63)==0) redm[wid] = m;
    __syncthreads();
    const float M = fmaxf(redm[tpair*2], redm[tpair*2+1]);
    const float e = __expf(score - M);
    float s = e;
#pragma unroll
    for (int off=32; off>0; off>>=1) s += __shfl_xor(s, off);
    if ((tid&63)==0) reds[wid] = s;
    __syncthreads();
    const float S = reds[tpair*2] + reds[tpair*2+1];
    const float alpha = e * fast_rcp(S);
    const int t = tch*16 + tl;
    const int g = (b*128 + t)*128 + n;
    out[g] = X[g] * alpha;
  }
}

// ---------------------------------------------------------------------------
extern "C" void kernel_launch(void* const* d_in, const int* in_sizes, int n_in,
                              void* d_out, int out_size, void* d_ws, size_t ws_size,
                              hipStream_t stream){
  (void)in_sizes; (void)n_in; (void)out_size; (void)ws_size;
  const float* X   = (const float*)d_in[0];
  const float* h0  = (const float*)d_in[1];
  const float* s0  = (const float*)d_in[2];
  const float* Wl  = (const float*)d_in[3];
  const float* Ul  = (const float*)d_in[4];
  const float* bl  = (const float*)d_in[5];
  const float* We  = (const float*)d_in[6];
  const float* bWe = (const float*)d_in[7];
  const float* Ue  = (const float*)d_in[8];
  const float* bUe = (const float*)d_in[9];
  const float* ve  = (const float*)d_in[10];
  // d_in[11] (b_ve) is softmax-shift-invariant: skipped.
  float* out = (float*)d_out;

  char* ws = (char*)d_ws;
  // layout (Ap aliases Uhp: Uhp dead after k2, Ap written by k3 which runs later)
  unsigned short* Wlt = (unsigned short*)(ws + 0);          // 2048x128 bf16 (512 KB)
  unsigned short* Wet = (unsigned short*)(ws + 524288);     // 128x1024 bf16 (256 KB)
  float*          UT  = (float*)(ws + 786432);              // 64x128x128 f32 (4 MB)
  unsigned short* hc  = (unsigned short*)(ws + 4980736);    // 8192x1024 bf16 (16 MB)
  float*          Uhp = (float*)(ws + 21757952);            // 4x64x2048 f32 (2 MB)
  float*          Ap  = (float*)(ws + 21757952);            // 4x8192x128 f32 (16 MB)

  transp_bf<<<dim3(32,2),  256, 0, stream>>>(Wl, Wlt, 128, 2048);
  transp_bf<<<dim3(2,16),  256, 0, stream>>>(We, Wet, 1024, 128);
  k1_part  <<<dim3(16,16), 256, 0, stream>>>(h0, Ul, Uhp);
  k2_mfma  <<<dim3(16,64), 256, 0, stream>>>(X, Wlt, Uhp, bl, s0, hc);
  k4_U     <<<dim3(2,64),  256, 0, stream>>>(X, Ue, bUe, UT);
  k3_mfma  <<<dim3(4,64),  256, 0, stream>>>(hc, Wet, Ap);
  k5_score <<<dim3(8,64),  256, 0, stream>>>(X, UT, Ap, bWe, ve, out);
}

// Round 3
// 117.036 us; speedup vs baseline: 2.1611x; 1.1358x over previous
//
#include <hip/hip_runtime.h>

// B=64, T=128, N=128, M=512, 4M=2048, BT=8192
typedef __attribute__((ext_vector_type(8))) short bfrag;   // 8 bf16 = 4 VGPR
typedef __attribute__((ext_vector_type(4))) float f32x4;

#define FMA4(A,S,V) {(A).x+=(S)*(V).x; (A).y+=(S)*(V).y; (A).z+=(S)*(V).z; (A).w+=(S)*(V).w;}

__device__ __forceinline__ float fast_rcp(float x){
#if __has_builtin(__builtin_amdgcn_rcpf)
  return __builtin_amdgcn_rcpf(x);
#else
  return 1.0f/x;
#endif
}
__device__ __forceinline__ float sigm(float x){ return fast_rcp(1.0f + __expf(-x)); }
__device__ __forceinline__ float tanh_f(float x){ return 1.0f - 2.0f*fast_rcp(__expf(2.0f*x) + 1.0f); }
__device__ __forceinline__ float bf2f(unsigned short u){ return __uint_as_float(((unsigned)u)<<16); }
__device__ __forceinline__ unsigned short f2bf(float f){
  unsigned u = __float_as_uint(f);
  return (unsigned short)((u + 0x7fffu + ((u>>16)&1u)) >> 16);
}
// async global->LDS, 16B per lane; LDS dest must be wave-uniform base + lane*16
__device__ __forceinline__ void gload16(const void* g, void* l){
  __builtin_amdgcn_global_load_lds((const __attribute__((address_space(1))) void*)g,
                                   (__attribute__((address_space(3))) void*)l, 16, 0, 0);
}

// Pade(5,4) tanh: x*(945+105t+t^2)/(945+420t+15t^2), t=x^2.  |err|<2.5e-5 on [-2,2]
__device__ __forceinline__ f32x4 clamp4(f32x4 x){
  f32x4 r;
  r.x = fminf(fmaxf(x.x,-3.f),3.f); r.y = fminf(fmaxf(x.y,-3.f),3.f);
  r.z = fminf(fmaxf(x.z,-3.f),3.f); r.w = fminf(fmaxf(x.w,-3.f),3.f);
  return r;
}
__device__ __forceinline__ f32x4 tanh4(f32x4 x){
  x = clamp4(x);
  f32x4 t = x*x;
  f32x4 num = t*(t + 105.f) + 945.f;
  f32x4 den = t*(t*15.f + 420.f) + 945.f;
  f32x4 r;
  r.x = fast_rcp(den.x); r.y = fast_rcp(den.y);
  r.z = fast_rcp(den.z); r.w = fast_rcp(den.w);
  return (x*num)*r;
}

// ---------------------------------------------------------------------------
// xconv: X f32 -> bf16 (1M elems, 8/thread, grid 512)
__global__ __launch_bounds__(256) void xconv(const float* __restrict__ X,
                                             unsigned short* __restrict__ Xbf){
  const int i = (blockIdx.x*256 + threadIdx.x)*8;
  float4 a = *(const float4*)&X[i];
  float4 b = *(const float4*)&X[i+4];
  ushort4 lo, hi;
  lo.x=f2bf(a.x); lo.y=f2bf(a.y); lo.z=f2bf(a.z); lo.w=f2bf(a.w);
  hi.x=f2bf(b.x); hi.y=f2bf(b.y); hi.z=f2bf(b.z); hi.w=f2bf(b.w);
  *(ushort4*)&Xbf[i] = lo; *(ushort4*)&Xbf[i+4] = hi;
}

// ---------------------------------------------------------------------------
// transpose f32 [K][N] -> bf16 [N][K].  grid (N/64, K/64), block 256
__global__ __launch_bounds__(256) void transp_bf(const float* __restrict__ in,
                                                 unsigned short* __restrict__ out,
                                                 int K, int N){
  __shared__ float t[64][68];
  const int tid = threadIdx.x;
  const int j0 = blockIdx.x*64, k0 = blockIdx.y*64;
#pragma unroll
  for (int i=0;i<4;i++){
    int idx = tid + i*256;
    int r = idx>>4, c4 = idx&15;
    *(float4*)&t[r][c4*4] = *(const float4*)&in[(k0+r)*N + j0 + c4*4];
  }
  __syncthreads();
#pragma unroll
  for (int i=0;i<4;i++){
    int idx = tid + i*256;
    int r = idx>>4, c4 = idx&15;
    ushort4 o;
    o.x = f2bf(t[c4*4+0][r]); o.y = f2bf(t[c4*4+1][r]);
    o.z = f2bf(t[c4*4+2][r]); o.w = f2bf(t[c4*4+3][r]);
    *(ushort4*)&out[(j0+r)*K + k0 + c4*4] = o;
  }
}

// ---------------------------------------------------------------------------
// K1: Uhp[kc][b][j] = sum_{k in kc} h0[b][k]*Ul[k][j]   (partials; bias in K2)
// grid (16 jc, 16 = 4 bc x 4 kc), block 256
__global__ __launch_bounds__(256) void k1_part(const float* __restrict__ h0,
                                               const float* __restrict__ Ul,
                                               float* __restrict__ Uhp){
  __shared__ float h0s[16][128];
  const int tid = threadIdx.x;
  const int jc = blockIdx.x;
  const int bc = blockIdx.y >> 2, kc = blockIdx.y & 3;
#pragma unroll
  for (int i=0;i<2;i++){
    int idx = tid + i*256;
    int bi = idx>>5, kq = idx&31;
    *(float4*)&h0s[bi][kq*4] = *(const float4*)&h0[(bc*16+bi)*512 + kc*128 + kq*4];
  }
  __syncthreads();
  const int jj = tid & 127, bh = tid >> 7;
  const int j = jc*128 + jj;
  float acc[8];
#pragma unroll
  for (int i=0;i<8;i++) acc[i]=0.f;
  for (int k=0;k<128;k+=4){
    float w0 = Ul[(kc*128+k+0)*2048 + j];
    float w1 = Ul[(kc*128+k+1)*2048 + j];
    float w2 = Ul[(kc*128+k+2)*2048 + j];
    float w3 = Ul[(kc*128+k+3)*2048 + j];
#pragma unroll
    for (int bi=0;bi<8;bi++){
      float4 h4 = *(const float4*)&h0s[bh*8+bi][k];
      acc[bi] += h4.x*w0 + h4.y*w1 + h4.z*w2 + h4.w*w3;
    }
  }
#pragma unroll
  for (int bi=0;bi<8;bi++)
    Uhp[kc*131072 + (bc*16 + bh*8 + bi)*2048 + j] = acc[bi];
}

// ---------------------------------------------------------------------------
// K2: z = X@Wl + Uh -> gates -> hc bf16.  MFMA 16x16x32 bf16, K=128 single stage.
// cols gate-interleaved: c -> q=c>>4, j = (q&3)*512 + mc*32 + ((q>>2)<<4) + (c&15)
// grid (16 mc, 64 b), block 256 (4 waves 2x2 of 64x64)
__global__ __launch_bounds__(256) void k2_mfma(const unsigned short* __restrict__ Xbf,
                                               const unsigned short* __restrict__ Wlt,
                                               const float* __restrict__ Uhp,
                                               const float* __restrict__ bl,
                                               const float* __restrict__ s0,
                                               unsigned short* __restrict__ hc){
  __shared__ __align__(16) char lds[65536];   // Xs [128][256B swz] | Ws [128][256B swz]
  const int tid = threadIdx.x;
  const int mc = blockIdx.x;       // 0..15
  const int b  = blockIdx.y;       // 0..63
  const int bt0 = b*128;
  const int lane = tid & 63, wave = tid >> 6;
  const int wr = wave >> 1, wc = wave & 1;

  // stage X via async copy; LDS linear, source pre-swizzled (granule G^(r&7))
#pragma unroll
  for (int i=0;i<8;i++){
    int g = tid + i*256;             // 2048 granules: r = g>>4, G = g&15
    int r = g>>4, G = g&15;
    gload16(Xbf + (bt0+r)*128 + ((G ^ (r&7))<<3), lds + g*16);
  }
#pragma unroll
  for (int i=0;i<8;i++){
    int g = tid + i*256;
    int c = g>>4, G = g&15;
    int q = c>>4;
    int j = (q&3)*512 + mc*32 + ((q>>2)<<4) + (c&15);
    gload16(Wlt + j*128 + ((G ^ (c&7))<<3), lds + 32768 + g*16);
  }
  __syncthreads();

  f32x4 acc[4][4];
#pragma unroll
  for (int mt=0;mt<4;mt++)
#pragma unroll
    for (int nt=0;nt<4;nt++) acc[mt][nt] = (f32x4){0.f,0.f,0.f,0.f};

#pragma unroll
  for (int ks=0;ks<4;ks++){
    const int kb = ks*64 + ((lane>>4)<<4);
    bfrag a[4], bb[4];
#pragma unroll
    for (int mt=0;mt<4;mt++){
      int r = wr*64 + mt*16 + (lane&15);
      a[mt] = *(const bfrag*)&lds[r*256 + (kb ^ ((r&7)<<4))];
    }
#pragma unroll
    for (int nt=0;nt<4;nt++){
      int c = wc*64 + nt*16 + (lane&15);
      bb[nt] = *(const bfrag*)&lds[32768 + c*256 + (kb ^ ((c&7)<<4))];
    }
#pragma unroll
    for (int mt=0;mt<4;mt++)
#pragma unroll
      for (int nt=0;nt<4;nt++)
        acc[mt][nt] = __builtin_amdgcn_mfma_f32_16x16x32_bf16(a[mt], bb[nt], acc[mt][nt], 0, 0, 0);
  }

  const int mloc = mc*32 + wc*16 + (lane&15);     // 0..511
  float uh[4];
#pragma unroll
  for (int g=0;g<4;g++){
    int j = g*512 + mloc;
    uh[g] = bl[j] + Uhp[0*131072 + b*2048 + j] + Uhp[1*131072 + b*2048 + j]
                  + Uhp[2*131072 + b*2048 + j] + Uhp[3*131072 + b*2048 + j];
  }
  const float s0v = s0[b*512 + mloc];
#pragma unroll
  for (int mt=0;mt<4;mt++){
#pragma unroll
    for (int reg=0;reg<4;reg++){
      int row = wr*64 + mt*16 + (lane>>4)*4 + reg;
      float zi = acc[mt][0][reg] + uh[0];
      float zf = acc[mt][1][reg] + uh[1];
      float zc = acc[mt][2][reg] + uh[2];
      float zo = acc[mt][3][reg] + uh[3];
      float fi = sigm(zi), ff = sigm(zf), fo = sigm(zo);
      float cv = ff*s0v + fi*tanh_f(zc);
      float hv = fo*tanh_f(cv);
      hc[(bt0+row)*1024 + mloc]       = f2bf(hv);
      hc[(bt0+row)*1024 + 512 + mloc] = f2bf(cv);
    }
  }
}

// ---------------------------------------------------------------------------
// K3: A = hc(bf16) @ Wet^T + bWe   (full K=1024, no split).  Tile 64x128.
// grid (128 rc), block 256 (4 waves 2x2 of 32x64)
__global__ __launch_bounds__(256) void k3_mfma(const unsigned short* __restrict__ hc,
                                               const unsigned short* __restrict__ Wet,
                                               const float* __restrict__ bWe,
                                               float* __restrict__ A){
  __shared__ __align__(16) char lds[49152];  // hcs 16KB [64][256B] | wes 32KB [128][256B]
  const int tid = threadIdx.x;
  const int rc = blockIdx.x;       // 0..127
  const int bt0 = rc*64;
  const int lane = tid & 63, wave = tid >> 6;
  const int wr = wave >> 1, wc = wave & 1;

  f32x4 acc[2][4];
#pragma unroll
  for (int mt=0;mt<2;mt++)
#pragma unroll
    for (int nt=0;nt<4;nt++) acc[mt][nt] = (f32x4){0.f,0.f,0.f,0.f};

  for (int ks=0; ks<8; ks++){
    const int k0 = ks*128;
#pragma unroll
    for (int i=0;i<4;i++){
      int g = tid + i*256;           // 1024 granules: 64 rows x 16
      int r = g>>4, G = g&15;
      gload16(hc + (bt0+r)*1024 + k0 + ((G ^ (r&7))<<3), lds + g*16);
    }
#pragma unroll
    for (int i=0;i<8;i++){
      int g = tid + i*256;           // 2048 granules: 128 n-rows x 16
      int nn = g>>4, G = g&15;
      gload16(Wet + nn*1024 + k0 + ((G ^ (nn&7))<<3), lds + 16384 + g*16);
    }
    __syncthreads();
#pragma unroll
    for (int kk=0;kk<4;kk++){
      const int kb = kk*64 + ((lane>>4)<<4);
      bfrag a[2], bb[4];
#pragma unroll
      for (int mt=0;mt<2;mt++){
        int r = wr*32 + mt*16 + (lane&15);
        a[mt] = *(const bfrag*)&lds[r*256 + (kb ^ ((r&7)<<4))];
      }
#pragma unroll
      for (int nt=0;nt<4;nt++){
        int nn = wc*64 + nt*16 + (lane&15);
        bb[nt] = *(const bfrag*)&lds[16384 + nn*256 + (kb ^ ((nn&7)<<4))];
      }
#pragma unroll
      for (int mt=0;mt<2;mt++)
#pragma unroll
        for (int nt=0;nt<4;nt++)
          acc[mt][nt] = __builtin_amdgcn_mfma_f32_16x16x32_bf16(a[mt], bb[nt], acc[mt][nt], 0, 0, 0);
    }
    __syncthreads();
  }
#pragma unroll
  for (int mt=0;mt<2;mt++)
#pragma unroll
    for (int reg=0;reg<4;reg++){
      int row = wr*32 + mt*16 + (lane>>4)*4 + reg;
#pragma unroll
      for (int nt=0;nt<4;nt++){
        int col = wc*64 + nt*16 + (lane&15);
        A[(bt0+row)*128 + col] = acc[mt][nt][reg] + bWe[col];
      }
    }
}

// ---------------------------------------------------------------------------
// K4: UTb[b][n][k] = bf16( sum_t X[b][t][n]*U_e[t][k] + b_Ue[k] )  (n-major!)
// grid (2 nh, 64 b), block 256
__global__ __launch_bounds__(256) void k4_U(const float* __restrict__ X,
                                            const float* __restrict__ Ue,
                                            const float* __restrict__ bUe,
                                            unsigned short* __restrict__ UTb){
  __shared__ float Xs[32][68];    // [t][n]
  __shared__ float Us[32][132];   // [t][k]
  const int tid = threadIdx.x;
  const int nh = blockIdx.x;      // 0..1
  const int b  = blockIdx.y;      // 0..63
  const int tr = tid>>4, tc = tid&15;
  float4 acc[8];
#pragma unroll
  for (int i=0;i<8;i++){ acc[i].x=0.f; acc[i].y=0.f; acc[i].z=0.f; acc[i].w=0.f; }

  for (int tk=0; tk<4; tk++){
#pragma unroll
    for (int i=0;i<2;i++){
      int idx = tid + i*256;
      int t = idx>>4, nq = idx&15;
      *(float4*)&Xs[t][nq*4] = *(const float4*)&X[(b*128 + tk*32 + t)*128 + nh*64 + nq*4];
    }
#pragma unroll
    for (int i=0;i<4;i++){
      int idx = tid + i*256;
      int t = idx>>5, kq = idx&31;
      *(float4*)&Us[t][kq*4] = *(const float4*)&Ue[(tk*32+t)*128 + kq*4];
    }
    __syncthreads();
#pragma unroll 4
    for (int t=0;t<32;t++){
      float4 xv = *(const float4*)&Xs[t][tr*4];
      float4 u0 = *(const float4*)&Us[t][tc*4];
      float4 u1 = *(const float4*)&Us[t][64 + tc*4];
      FMA4(acc[0], u0.x, xv); FMA4(acc[1], u0.y, xv); FMA4(acc[2], u0.z, xv); FMA4(acc[3], u0.w, xv);
      FMA4(acc[4], u1.x, xv); FMA4(acc[5], u1.y, xv); FMA4(acc[6], u1.z, xv); FMA4(acc[7], u1.w, xv);
    }
    __syncthreads();
  }
  // transposed scalar bf16 stores: UTb[b][n][k]
#pragma unroll
  for (int kk=0; kk<8; kk++){
    const int k = (kk<4) ? (tc*4+kk) : (64 + tc*4 + (kk-4));
    const float bu = bUe[k];
    float av[4] = {acc[kk].x, acc[kk].y, acc[kk].z, acc[kk].w};
#pragma unroll
    for (int j=0;j<4;j++){
      int n = nh*64 + tr*4 + j;
      UTb[(b*128 + n)*128 + k] = f2bf(av[j] + bu);
    }
  }
}

// ---------------------------------------------------------------------------
// K5: scores[t,n] = sum_k tanh(A[t,k]+U[n,k])*v[k]; softmax over n; out = X*alpha
// Un bf16 [n][k] swizzled in LDS; u,v in regs reused across 8 t; Pade tanh.
// grid (8 tch, 64 b), block 256 = (tpair 2) x (n 128)
__global__ __launch_bounds__(256) void k5_score(const float* __restrict__ X,
                                                const unsigned short* __restrict__ UTb,
                                                const float* __restrict__ A,
                                                const float* __restrict__ ve,
                                                float* __restrict__ out){
  __shared__ __align__(16) unsigned short Un[128*128];  // 32KB, [n][256B swz]
  __shared__ __align__(16) float As[16*128];            // 8KB
  __shared__ __align__(16) float vs[128];
  __shared__ float redm[4][8], reds[4][8];
  const int tid = threadIdx.x;
  const int tch = blockIdx.x;     // 0..7
  const int b   = blockIdx.y;     // 0..63
  const int tpair = tid>>7, n = tid&127, wid = tid>>6;

  {
    const unsigned short* src = UTb + b*16384;
#pragma unroll
    for (int i=0;i<8;i++){
      int g = tid + i*256;            // 2048 granules: nn = g>>4, G = g&15
      int nn = g>>4, G = g&15;
      gload16(src + nn*128 + ((G ^ (nn&7))<<3), (char*)Un + g*16);
    }
    const float* asrc = A + (b*128 + tch*16)*128;
#pragma unroll
    for (int i=0;i<2;i++){
      int g = tid + i*256;            // 512 granules, linear
      gload16(asrc + g*4, (char*)As + g*16);
    }
    if (tid < 128) vs[tid] = ve[tid];
  }
  __syncthreads();

  f32x4 sc[8];
#pragma unroll
  for (int tt=0;tt<8;tt++) sc[tt] = (f32x4){0.f,0.f,0.f,0.f};

  const char* Urow = (const char*)Un + n*256;
  const int swz = (n&7)<<4;
#pragma unroll 2
  for (int k8=0; k8<16; k8++){
    uint4 u = *(const uint4*)(Urow + ((k8*16) ^ swz));
    f32x4 ua, ub;
    ua.x = __uint_as_float(u.x<<16); ua.y = __uint_as_float(u.x & 0xffff0000u);
    ua.z = __uint_as_float(u.y<<16); ua.w = __uint_as_float(u.y & 0xffff0000u);
    ub.x = __uint_as_float(u.z<<16); ub.y = __uint_as_float(u.z & 0xffff0000u);
    ub.z = __uint_as_float(u.w<<16); ub.w = __uint_as_float(u.w & 0xffff0000u);
    const f32x4 va = *(const f32x4*)&vs[k8*8];
    const f32x4 vb = *(const f32x4*)&vs[k8*8+4];
#pragma unroll
    for (int tt=0; tt<8; tt++){
      const float* Ar = &As[(tt*2+tpair)*128 + k8*8];
      f32x4 aa = *(const f32x4*)Ar;
      f32x4 ab = *(const f32x4*)(Ar+4);
      sc[tt] += tanh4(aa + ua)*va;
      sc[tt] += tanh4(ab + ub)*vb;
    }
  }

  // batched softmax over n=128 (2 waves per t)
  float sv[8];
#pragma unroll
  for (int tt=0;tt<8;tt++){
    float s = (sc[tt].x + sc[tt].y) + (sc[tt].z + sc[tt].w);
    sv[tt] = s;
    float m = s;
#pragma unroll
    for (int off=32; off>0; off>>=1) m = fmaxf(m, __shfl_xor(m, off));
    if ((tid&63)==0) redm[wid][tt] = m;
  }
  __syncthreads();
  float ev[8];
#pragma unroll
  for (int tt=0;tt<8;tt++){
    const float M = fmaxf(redm[tpair*2][tt], redm[tpair*2+1][tt]);
    float e = __expf(sv[tt] - M);
    ev[tt] = e;
    float s = e;
#pragma unroll
    for (int off=32; off>0; off>>=1) s += __shfl_xor(s, off);
    if ((tid&63)==0) reds[wid][tt] = s;
  }
  __syncthreads();
#pragma unroll
  for (int tt=0;tt<8;tt++){
    const float S = reds[tpair*2][tt] + reds[tpair*2+1][tt];
    const float alpha = ev[tt] * fast_rcp(S);
    const int t = tch*16 + tt*2 + tpair;
    const int g = (b*128 + t)*128 + n;
    out[g] = X[g] * alpha;
  }
}

// ---------------------------------------------------------------------------
extern "C" void kernel_launch(void* const* d_in, const int* in_sizes, int n_in,
                              void* d_out, int out_size, void* d_ws, size_t ws_size,
                              hipStream_t stream){
  (void)in_sizes; (void)n_in; (void)out_size; (void)ws_size;
  const float* X   = (const float*)d_in[0];
  const float* h0  = (const float*)d_in[1];
  const float* s0  = (const float*)d_in[2];
  const float* Wl  = (const float*)d_in[3];
  const float* Ul  = (const float*)d_in[4];
  const float* bl  = (const float*)d_in[5];
  const float* We  = (const float*)d_in[6];
  const float* bWe = (const float*)d_in[7];
  const float* Ue  = (const float*)d_in[8];
  const float* bUe = (const float*)d_in[9];
  const float* ve  = (const float*)d_in[10];
  // d_in[11] (b_ve) is softmax-shift-invariant: skipped.
  float* out = (float*)d_out;

  char* ws = (char*)d_ws;
  unsigned short* Wlt = (unsigned short*)(ws + 0);          // 2048x128 bf16 (512 KB)
  unsigned short* Wet = (unsigned short*)(ws + 524288);     // 128x1024 bf16 (256 KB)
  unsigned short* Xbf = (unsigned short*)(ws + 786432);     // 8192x128 bf16 (2 MB)
  unsigned short* UTb = (unsigned short*)(ws + 2883584);    // 64x128x128 bf16 (2 MB)
  unsigned short* hc  = (unsigned short*)(ws + 4980736);    // 8192x1024 bf16 (16 MB)
  float*          Uhp = (float*)(ws + 21757952);            // 4x64x2048 f32 (2 MB)
  float*          A   = (float*)(ws + 23855104);            // 8192x128 f32 (4 MB)

  xconv    <<<dim3(512),    256, 0, stream>>>(X, Xbf);
  transp_bf<<<dim3(32,2),   256, 0, stream>>>(Wl, Wlt, 128, 2048);
  transp_bf<<<dim3(2,16),   256, 0, stream>>>(We, Wet, 1024, 128);
  k1_part  <<<dim3(16,16),  256, 0, stream>>>(h0, Ul, Uhp);
  k4_U     <<<dim3(2,64),   256, 0, stream>>>(X, Ue, bUe, UTb);
  k2_mfma  <<<dim3(16,64),  256, 0, stream>>>(Xbf, Wlt, Uhp, bl, s0, hc);
  k3_mfma  <<<dim3(128),    256, 0, stream>>>(hc, Wet, bWe, A);
  k5_score <<<dim3(8,64),   256, 0, stream>>>(X, UTb, A, ve, out);
}

// Round 4
// 89.813 us; speedup vs baseline: 2.8161x; 1.3031x over previous
//
#include <hip/hip_runtime.h>

// B=64, T=128, N=128, M=512, 4M=2048, BT=8192
typedef __attribute__((ext_vector_type(8))) short bfrag;   // 8 bf16 = 4 VGPR
typedef __attribute__((ext_vector_type(4))) float f32x4;

#define FMA4(A,S,V) {(A).x+=(S)*(V).x; (A).y+=(S)*(V).y; (A).z+=(S)*(V).z; (A).w+=(S)*(V).w;}

// 2*log2(e): z' = C_SCALE*(A+U) so tanh(A+U) = 1 - 2/(exp2(z')+1)
#define C_SCALE 2.885390081777926815f

__device__ __forceinline__ float fast_rcp(float x){
#if __has_builtin(__builtin_amdgcn_rcpf)
  return __builtin_amdgcn_rcpf(x);
#else
  return 1.0f/x;
#endif
}
__device__ __forceinline__ float fexp2(float x){
#if __has_builtin(__builtin_amdgcn_exp2f)
  return __builtin_amdgcn_exp2f(x);
#else
  return exp2f(x);
#endif
}
__device__ __forceinline__ float sigm(float x){ return fast_rcp(1.0f + __expf(-x)); }
__device__ __forceinline__ float tanh_f(float x){ return 1.0f - 2.0f*fast_rcp(__expf(2.0f*x) + 1.0f); }
__device__ __forceinline__ unsigned short f2bf(float f){
  unsigned u = __float_as_uint(f);
  return (unsigned short)((u + 0x7fffu + ((u>>16)&1u)) >> 16);
}
// async global->LDS, 16B per lane; LDS dest must be wave-uniform base + lane*16
__device__ __forceinline__ void gload16(const void* g, void* l){
  __builtin_amdgcn_global_load_lds((const __attribute__((address_space(1))) void*)g,
                                   (__attribute__((address_space(3))) void*)l, 16, 0, 0);
}

// ---------------------------------------------------------------------------
// PREP: fused { xconv (512) | Wl transpose (64) | We transpose (32) | k1 (256) }
// grid 864, block 256
__global__ __launch_bounds__(256) void prep(const float* __restrict__ X,
                                            unsigned short* __restrict__ Xbf,
                                            const float* __restrict__ Wl,
                                            unsigned short* __restrict__ Wlt,
                                            const float* __restrict__ We,
                                            unsigned short* __restrict__ Wet,
                                            const float* __restrict__ h0,
                                            const float* __restrict__ Ul,
                                            float* __restrict__ Uhp){
  __shared__ __align__(16) float sh[64*68];   // 17408 B, reused per branch
  const int tid = threadIdx.x;
  const int bid = blockIdx.x;

  if (bid < 512){                       // ---- xconv: X f32 -> bf16
    const int i = (bid*256 + tid)*8;
    float4 a = *(const float4*)&X[i];
    float4 b = *(const float4*)&X[i+4];
    ushort4 lo, hi;
    lo.x=f2bf(a.x); lo.y=f2bf(a.y); lo.z=f2bf(a.z); lo.w=f2bf(a.w);
    hi.x=f2bf(b.x); hi.y=f2bf(b.y); hi.z=f2bf(b.z); hi.w=f2bf(b.w);
    *(ushort4*)&Xbf[i] = lo; *(ushort4*)&Xbf[i+4] = hi;
  } else if (bid < 608){                // ---- transpose f32 [K][N] -> bf16 [N][K]
    const float* in; unsigned short* outp; int K, N, j0, k0;
    if (bid < 576){ int r = bid-512; in = Wl; outp = Wlt; K = 128;  N = 2048; j0 = (r&31)*64; k0 = (r>>5)*64; }
    else          { int r = bid-576; in = We; outp = Wet; K = 1024; N = 128;  j0 = (r&1)*64;  k0 = (r>>1)*64; }
    float (*t)[68] = (float(*)[68])sh;
#pragma unroll
    for (int i=0;i<4;i++){
      int idx = tid + i*256;
      int r = idx>>4, c4 = idx&15;
      *(float4*)&t[r][c4*4] = *(const float4*)&in[(k0+r)*N + j0 + c4*4];
    }
    __syncthreads();
#pragma unroll
    for (int i=0;i<4;i++){
      int idx = tid + i*256;
      int r = idx>>4, c4 = idx&15;
      ushort4 o;
      o.x = f2bf(t[c4*4+0][r]); o.y = f2bf(t[c4*4+1][r]);
      o.z = f2bf(t[c4*4+2][r]); o.w = f2bf(t[c4*4+3][r]);
      *(ushort4*)&outp[(j0+r)*K + k0 + c4*4] = o;
    }
  } else {                              // ---- k1: Uhp[kc][b][j] partials
    const int r = bid - 608;
    const int jc = r & 15;
    const int bc = (r>>4) >> 2, kc = (r>>4) & 3;
    float (*h0s)[128] = (float(*)[128])sh;
#pragma unroll
    for (int i=0;i<2;i++){
      int idx = tid + i*256;
      int bi = idx>>5, kq = idx&31;
      *(float4*)&h0s[bi][kq*4] = *(const float4*)&h0[(bc*16+bi)*512 + kc*128 + kq*4];
    }
    __syncthreads();
    const int jj = tid & 127, bh = tid >> 7;
    const int j = jc*128 + jj;
    float acc[8];
#pragma unroll
    for (int i=0;i<8;i++) acc[i]=0.f;
    for (int k=0;k<128;k+=4){
      float w0 = Ul[(kc*128+k+0)*2048 + j];
      float w1 = Ul[(kc*128+k+1)*2048 + j];
      float w2 = Ul[(kc*128+k+2)*2048 + j];
      float w3 = Ul[(kc*128+k+3)*2048 + j];
#pragma unroll
      for (int bi=0;bi<8;bi++){
        float4 h4 = *(const float4*)&h0s[bh*8+bi][k];
        acc[bi] += h4.x*w0 + h4.y*w1 + h4.z*w2 + h4.w*w3;
      }
    }
#pragma unroll
    for (int bi=0;bi<8;bi++)
      Uhp[kc*131072 + (bc*16 + bh*8 + bi)*2048 + j] = acc[bi];
  }
}

// ---------------------------------------------------------------------------
// K2: z = X@Wl + Uh -> gates -> hc bf16.  MFMA 16x16x32 bf16, K=128 single stage.
// grid (16 mc, 64 b), block 256 (4 waves 2x2 of 64x64)
__global__ __launch_bounds__(256) void k2_mfma(const unsigned short* __restrict__ Xbf,
                                               const unsigned short* __restrict__ Wlt,
                                               const float* __restrict__ Uhp,
                                               const float* __restrict__ bl,
                                               const float* __restrict__ s0,
                                               unsigned short* __restrict__ hc){
  __shared__ __align__(16) char lds[65536];   // Xs [128][256B swz] | Ws [128][256B swz]
  const int tid = threadIdx.x;
  const int mc = blockIdx.x;       // 0..15
  const int b  = blockIdx.y;       // 0..63
  const int bt0 = b*128;
  const int lane = tid & 63, wave = tid >> 6;
  const int wr = wave >> 1, wc = wave & 1;

#pragma unroll
  for (int i=0;i<8;i++){
    int g = tid + i*256;             // 2048 granules: r = g>>4, G = g&15
    int r = g>>4, G = g&15;
    gload16(Xbf + (bt0+r)*128 + ((G ^ (r&7))<<3), lds + g*16);
  }
#pragma unroll
  for (int i=0;i<8;i++){
    int g = tid + i*256;
    int c = g>>4, G = g&15;
    int q = c>>4;
    int j = (q&3)*512 + mc*32 + ((q>>2)<<4) + (c&15);
    gload16(Wlt + j*128 + ((G ^ (c&7))<<3), lds + 32768 + g*16);
  }
  __syncthreads();

  f32x4 acc[4][4];
#pragma unroll
  for (int mt=0;mt<4;mt++)
#pragma unroll
    for (int nt=0;nt<4;nt++) acc[mt][nt] = (f32x4){0.f,0.f,0.f,0.f};

#pragma unroll
  for (int ks=0;ks<4;ks++){
    const int kb = ks*64 + ((lane>>4)<<4);
    bfrag a[4], bb[4];
#pragma unroll
    for (int mt=0;mt<4;mt++){
      int r = wr*64 + mt*16 + (lane&15);
      a[mt] = *(const bfrag*)&lds[r*256 + (kb ^ ((r&7)<<4))];
    }
#pragma unroll
    for (int nt=0;nt<4;nt++){
      int c = wc*64 + nt*16 + (lane&15);
      bb[nt] = *(const bfrag*)&lds[32768 + c*256 + (kb ^ ((c&7)<<4))];
    }
#pragma unroll
    for (int mt=0;mt<4;mt++)
#pragma unroll
      for (int nt=0;nt<4;nt++)
        acc[mt][nt] = __builtin_amdgcn_mfma_f32_16x16x32_bf16(a[mt], bb[nt], acc[mt][nt], 0, 0, 0);
  }

  const int mloc = mc*32 + wc*16 + (lane&15);     // 0..511
  float uh[4];
#pragma unroll
  for (int g=0;g<4;g++){
    int j = g*512 + mloc;
    uh[g] = bl[j] + Uhp[0*131072 + b*2048 + j] + Uhp[1*131072 + b*2048 + j]
                  + Uhp[2*131072 + b*2048 + j] + Uhp[3*131072 + b*2048 + j];
  }
  const float s0v = s0[b*512 + mloc];
#pragma unroll
  for (int mt=0;mt<4;mt++){
#pragma unroll
    for (int reg=0;reg<4;reg++){
      int row = wr*64 + mt*16 + (lane>>4)*4 + reg;
      float zi = acc[mt][0][reg] + uh[0];
      float zf = acc[mt][1][reg] + uh[1];
      float zc = acc[mt][2][reg] + uh[2];
      float zo = acc[mt][3][reg] + uh[3];
      float fi = sigm(zi), ff = sigm(zf), fo = sigm(zo);
      float cv = ff*s0v + fi*tanh_f(zc);
      float hv = fo*tanh_f(cv);
      hc[(bt0+row)*1024 + mloc]       = f2bf(hv);
      hc[(bt0+row)*1024 + 512 + mloc] = f2bf(cv);
    }
  }
}

// ---------------------------------------------------------------------------
// K3: A = C_SCALE*(hc(bf16) @ Wet^T + bWe)   (full K=1024).  Tile 64x128.
// grid (128 rc), block 256 (4 waves 2x2 of 32x64)
__global__ __launch_bounds__(256) void k3_mfma(const unsigned short* __restrict__ hc,
                                               const unsigned short* __restrict__ Wet,
                                               const float* __restrict__ bWe,
                                               float* __restrict__ A){
  __shared__ __align__(16) char lds[49152];  // hcs 16KB [64][256B] | wes 32KB [128][256B]
  const int tid = threadIdx.x;
  const int rc = blockIdx.x;       // 0..127
  const int bt0 = rc*64;
  const int lane = tid & 63, wave = tid >> 6;
  const int wr = wave >> 1, wc = wave & 1;

  f32x4 acc[2][4];
#pragma unroll
  for (int mt=0;mt<2;mt++)
#pragma unroll
    for (int nt=0;nt<4;nt++) acc[mt][nt] = (f32x4){0.f,0.f,0.f,0.f};

  for (int ks=0; ks<8; ks++){
    const int k0 = ks*128;
#pragma unroll
    for (int i=0;i<4;i++){
      int g = tid + i*256;           // 1024 granules: 64 rows x 16
      int r = g>>4, G = g&15;
      gload16(hc + (bt0+r)*1024 + k0 + ((G ^ (r&7))<<3), lds + g*16);
    }
#pragma unroll
    for (int i=0;i<8;i++){
      int g = tid + i*256;           // 2048 granules: 128 n-rows x 16
      int nn = g>>4, G = g&15;
      gload16(Wet + nn*1024 + k0 + ((G ^ (nn&7))<<3), lds + 16384 + g*16);
    }
    __syncthreads();
#pragma unroll
    for (int kk=0;kk<4;kk++){
      const int kb = kk*64 + ((lane>>4)<<4);
      bfrag a[2], bb[4];
#pragma unroll
      for (int mt=0;mt<2;mt++){
        int r = wr*32 + mt*16 + (lane&15);
        a[mt] = *(const bfrag*)&lds[r*256 + (kb ^ ((r&7)<<4))];
      }
#pragma unroll
      for (int nt=0;nt<4;nt++){
        int nn = wc*64 + nt*16 + (lane&15);
        bb[nt] = *(const bfrag*)&lds[16384 + nn*256 + (kb ^ ((nn&7)<<4))];
      }
#pragma unroll
      for (int mt=0;mt<2;mt++)
#pragma unroll
        for (int nt=0;nt<4;nt++)
          acc[mt][nt] = __builtin_amdgcn_mfma_f32_16x16x32_bf16(a[mt], bb[nt], acc[mt][nt], 0, 0, 0);
    }
    __syncthreads();
  }
#pragma unroll
  for (int mt=0;mt<2;mt++)
#pragma unroll
    for (int reg=0;reg<4;reg++){
      int row = wr*32 + mt*16 + (lane>>4)*4 + reg;
#pragma unroll
      for (int nt=0;nt<4;nt++){
        int col = wc*64 + nt*16 + (lane&15);
        A[(bt0+row)*128 + col] = C_SCALE*(acc[mt][nt][reg] + bWe[col]);
      }
    }
}

// ---------------------------------------------------------------------------
// K4: UTb[b][n][k] = bf16( C_SCALE*(sum_t X[b][t][n]*U_e[t][k] + b_Ue[k]) )
// grid (2 nh, 64 b), block 256
__global__ __launch_bounds__(256) void k4_U(const float* __restrict__ X,
                                            const float* __restrict__ Ue,
                                            const float* __restrict__ bUe,
                                            unsigned short* __restrict__ UTb){
  __shared__ float Xs[32][68];    // [t][n]
  __shared__ float Us[32][132];   // [t][k]
  const int tid = threadIdx.x;
  const int nh = blockIdx.x;      // 0..1
  const int b  = blockIdx.y;      // 0..63
  const int tr = tid>>4, tc = tid&15;
  float4 acc[8];
#pragma unroll
  for (int i=0;i<8;i++){ acc[i].x=0.f; acc[i].y=0.f; acc[i].z=0.f; acc[i].w=0.f; }

  for (int tk=0; tk<4; tk++){
#pragma unroll
    for (int i=0;i<2;i++){
      int idx = tid + i*256;
      int t = idx>>4, nq = idx&15;
      *(float4*)&Xs[t][nq*4] = *(const float4*)&X[(b*128 + tk*32 + t)*128 + nh*64 + nq*4];
    }
#pragma unroll
    for (int i=0;i<4;i++){
      int idx = tid + i*256;
      int t = idx>>5, kq = idx&31;
      *(float4*)&Us[t][kq*4] = *(const float4*)&Ue[(tk*32+t)*128 + kq*4];
    }
    __syncthreads();
#pragma unroll 4
    for (int t=0;t<32;t++){
      float4 xv = *(const float4*)&Xs[t][tr*4];
      float4 u0 = *(const float4*)&Us[t][tc*4];
      float4 u1 = *(const float4*)&Us[t][64 + tc*4];
      FMA4(acc[0], u0.x, xv); FMA4(acc[1], u0.y, xv); FMA4(acc[2], u0.z, xv); FMA4(acc[3], u0.w, xv);
      FMA4(acc[4], u1.x, xv); FMA4(acc[5], u1.y, xv); FMA4(acc[6], u1.z, xv); FMA4(acc[7], u1.w, xv);
    }
    __syncthreads();
  }
#pragma unroll
  for (int kk=0; kk<8; kk++){
    const int k = (kk<4) ? (tc*4+kk) : (64 + tc*4 + (kk-4));
    const float bu = bUe[k];
    float av[4] = {acc[kk].x, acc[kk].y, acc[kk].z, acc[kk].w};
#pragma unroll
    for (int j=0;j<4;j++){
      int n = nh*64 + tr*4 + j;
      UTb[(b*128 + n)*128 + k] = f2bf(C_SCALE*(av[j] + bu));
    }
  }
}

// ---------------------------------------------------------------------------
// K5: score'[t,n] = -2 * sum_k v[k] / (exp2(A'[t,k]+U'[n,k]) + 1)
//     (A', U' pre-scaled by 2*log2e; sum_k v const cancels in softmax)
// softmax over n; out = X*alpha.  grid (16 tch of 8 t, 64 b), block 256.
__global__ __launch_bounds__(256) void k5_score(const float* __restrict__ X,
                                                const unsigned short* __restrict__ UTb,
                                                const float* __restrict__ A,
                                                const float* __restrict__ ve,
                                                float* __restrict__ out){
  __shared__ __align__(16) unsigned short Un[128*128];  // 32KB, [n][256B swz]
  __shared__ __align__(16) float As[8*128];             // 4KB
  __shared__ __align__(16) float vs[128];
  __shared__ float redm[4][4], reds[4][4];
  const int tid = threadIdx.x;
  const int tch = blockIdx.x;     // 0..15
  const int b   = blockIdx.y;     // 0..63
  const int tpair = tid>>7, n = tid&127, wid = tid>>6;

  {
    const unsigned short* src = UTb + b*16384;
#pragma unroll
    for (int i=0;i<8;i++){
      int g = tid + i*256;            // 2048 granules: nn = g>>4, G = g&15
      int nn = g>>4, G = g&15;
      gload16(src + nn*128 + ((G ^ (nn&7))<<3), (char*)Un + g*16);
    }
    const float* asrc = A + (b*128 + tch*8)*128;   // 1024 floats = 256 granules
    gload16(asrc + tid*4, (char*)As + tid*16);
    if (tid < 128) vs[tid] = ve[tid];
  }
  __syncthreads();

  f32x4 sc[4];
#pragma unroll
  for (int tt=0;tt<4;tt++) sc[tt] = (f32x4){0.f,0.f,0.f,0.f};

  const char* Urow = (const char*)Un + n*256;
  const int swz = (n&7)<<4;
#pragma unroll 4
  for (int k8=0; k8<16; k8++){
    uint4 u = *(const uint4*)(Urow + ((k8*16) ^ swz));
    f32x4 ua, ub;
    ua.x = __uint_as_float(u.x<<16); ua.y = __uint_as_float(u.x & 0xffff0000u);
    ua.z = __uint_as_float(u.y<<16); ua.w = __uint_as_float(u.y & 0xffff0000u);
    ub.x = __uint_as_float(u.z<<16); ub.y = __uint_as_float(u.z & 0xffff0000u);
    ub.z = __uint_as_float(u.w<<16); ub.w = __uint_as_float(u.w & 0xffff0000u);
    const f32x4 va = *(const f32x4*)&vs[k8*8];
    const f32x4 vb = *(const f32x4*)&vs[k8*8+4];
#pragma unroll
    for (int tt=0; tt<4; tt++){
      const float* Ar = &As[(tt*2+tpair)*128 + k8*8];
      f32x4 aa = *(const f32x4*)Ar;
      f32x4 ab = *(const f32x4*)(Ar+4);
      f32x4 za = aa + ua, zb = ab + ub;
      f32x4 ra, rb;
      ra.x = fast_rcp(fexp2(za.x)+1.f); ra.y = fast_rcp(fexp2(za.y)+1.f);
      ra.z = fast_rcp(fexp2(za.z)+1.f); ra.w = fast_rcp(fexp2(za.w)+1.f);
      rb.x = fast_rcp(fexp2(zb.x)+1.f); rb.y = fast_rcp(fexp2(zb.y)+1.f);
      rb.z = fast_rcp(fexp2(zb.z)+1.f); rb.w = fast_rcp(fexp2(zb.w)+1.f);
      sc[tt] += va*ra;
      sc[tt] += vb*rb;
    }
  }

  // batched softmax over n=128 (2 waves per t)
  float sv[4];
#pragma unroll
  for (int tt=0;tt<4;tt++){
    float s = -2.f*((sc[tt].x + sc[tt].y) + (sc[tt].z + sc[tt].w));
    sv[tt] = s;
    float m = s;
#pragma unroll
    for (int off=32; off>0; off>>=1) m = fmaxf(m, __shfl_xor(m, off));
    if ((tid&63)==0) redm[wid][tt] = m;
  }
  __syncthreads();
  float evv[4];
#pragma unroll
  for (int tt=0;tt<4;tt++){
    const float M = fmaxf(redm[tpair*2][tt], redm[tpair*2+1][tt]);
    float e = __expf(sv[tt] - M);
    evv[tt] = e;
    float s = e;
#pragma unroll
    for (int off=32; off>0; off>>=1) s += __shfl_xor(s, off);
    if ((tid&63)==0) reds[wid][tt] = s;
  }
  __syncthreads();
#pragma unroll
  for (int tt=0;tt<4;tt++){
    const float S = reds[tpair*2][tt] + reds[tpair*2+1][tt];
    const float alpha = evv[tt] * fast_rcp(S);
    const int t = tch*8 + tt*2 + tpair;
    const int g = (b*128 + t)*128 + n;
    out[g] = X[g] * alpha;
  }
}

// ---------------------------------------------------------------------------
extern "C" void kernel_launch(void* const* d_in, const int* in_sizes, int n_in,
                              void* d_out, int out_size, void* d_ws, size_t ws_size,
                              hipStream_t stream){
  (void)in_sizes; (void)n_in; (void)out_size; (void)ws_size;
  const float* X   = (const float*)d_in[0];
  const float* h0  = (const float*)d_in[1];
  const float* s0  = (const float*)d_in[2];
  const float* Wl  = (const float*)d_in[3];
  const float* Ul  = (const float*)d_in[4];
  const float* bl  = (const float*)d_in[5];
  const float* We  = (const float*)d_in[6];
  const float* bWe = (const float*)d_in[7];
  const float* Ue  = (const float*)d_in[8];
  const float* bUe = (const float*)d_in[9];
  const float* ve  = (const float*)d_in[10];
  // d_in[11] (b_ve) is softmax-shift-invariant: skipped.
  float* out = (float*)d_out;

  char* ws = (char*)d_ws;
  unsigned short* Wlt = (unsigned short*)(ws + 0);          // 2048x128 bf16 (512 KB)
  unsigned short* Wet = (unsigned short*)(ws + 524288);     // 128x1024 bf16 (256 KB)
  unsigned short* Xbf = (unsigned short*)(ws + 786432);     // 8192x128 bf16 (2 MB)
  unsigned short* UTb = (unsigned short*)(ws + 2883584);    // 64x128x128 bf16 (2 MB)
  unsigned short* hc  = (unsigned short*)(ws + 4980736);    // 8192x1024 bf16 (16 MB)
  float*          Uhp = (float*)(ws + 21757952);            // 4x64x2048 f32 (2 MB)
  float*          A   = (float*)(ws + 23855104);            // 8192x128 f32 (4 MB)

  prep     <<<dim3(864),    256, 0, stream>>>(X, Xbf, Wl, Wlt, We, Wet, h0, Ul, Uhp);
  k4_U     <<<dim3(2,64),   256, 0, stream>>>(X, Ue, bUe, UTb);
  k2_mfma  <<<dim3(16,64),  256, 0, stream>>>(Xbf, Wlt, Uhp, bl, s0, hc);
  k3_mfma  <<<dim3(128),    256, 0, stream>>>(hc, Wet, bWe, A);
  k5_score <<<dim3(16,64),  256, 0, stream>>>(X, UTb, A, ve, out);
}